// Round 1
// baseline (705.706 us; speedup 1.0000x reference)
//
#include <hip/hip_runtime.h>
#include <math.h>

namespace {

constexpr int B    = 128;
constexpr int H    = 1024;
constexpr int V    = 32000;
constexpr int WSZ  = 10;
constexpr int MAXW = 2 * WSZ + 1;   // 21

__device__ __forceinline__ float sigf(float x) { return 1.0f / (1.0f + expf(-x)); }

// ---------------------------------------------------------------------------
// Generic fp32 GEMM: C[128 x N] = A1[128 x K1] @ W1^T + A2[128 x K2] @ W2^T + b1 + b2
// W row-major with leading dim ldw (row n starts at W + n*ldw).
// Block: 256 threads, computes 128 rows x 32 cols. K-chunks of 32 staged in LDS
// transposed so the inner loop is float4 LDS reads.
// ---------------------------------------------------------------------------
__global__ void gemm128(const float* __restrict__ A1, int K1,
                        const float* __restrict__ W1, int ldw1,
                        const float* __restrict__ A2, int K2,
                        const float* __restrict__ W2, int ldw2,
                        const float* __restrict__ bias1,
                        const float* __restrict__ bias2,
                        float* __restrict__ C, int N)
{
    __shared__ float Ast[32][132];   // [k][row], padded
    __shared__ float Wst[32][36];    // [k][col], padded
    const int t  = threadIdx.x;
    const int bn = blockIdx.x * 32;
    const int tcol = t & 7;          // 8 col groups
    const int trow = t >> 3;         // 32 row groups
    const int c0 = tcol * 4;
    const int r0 = trow * 4;
    float acc[4][4] = {};

    const int Ktot = K1 + K2;
    for (int kc = 0; kc < Ktot; kc += 32) {
        const float* A; const float* W; int lda, ldw, ko;
        if (kc < K1) { A = A1; lda = K1; W = W1; ldw = ldw1; ko = kc; }
        else         { A = A2; lda = K2; W = W2; ldw = ldw2; ko = kc - K1; }
        #pragma unroll
        for (int i = 0; i < 16; ++i) {          // 128x32 A tile
            int e = t + i * 256;
            int b = e >> 5, k = e & 31;
            Ast[k][b] = A[(size_t)b * lda + ko + k];
        }
        #pragma unroll
        for (int i = 0; i < 4; ++i) {           // 32x32 W tile
            int e = t + i * 256;
            int n = e >> 5, k = e & 31;
            Wst[k][n] = W[(size_t)(bn + n) * ldw + ko + k];
        }
        __syncthreads();
        #pragma unroll
        for (int k = 0; k < 32; ++k) {
            const float4 av = *(const float4*)&Ast[k][r0];
            const float4 wv = *(const float4*)&Wst[k][c0];
            acc[0][0] += av.x * wv.x; acc[0][1] += av.x * wv.y;
            acc[0][2] += av.x * wv.z; acc[0][3] += av.x * wv.w;
            acc[1][0] += av.y * wv.x; acc[1][1] += av.y * wv.y;
            acc[1][2] += av.y * wv.z; acc[1][3] += av.y * wv.w;
            acc[2][0] += av.z * wv.x; acc[2][1] += av.z * wv.y;
            acc[2][2] += av.z * wv.z; acc[2][3] += av.z * wv.w;
            acc[3][0] += av.w * wv.x; acc[3][1] += av.w * wv.y;
            acc[3][2] += av.w * wv.z; acc[3][3] += av.w * wv.w;
        }
        __syncthreads();
    }

    #pragma unroll
    for (int j = 0; j < 4; ++j) {
        float bv = 0.f;
        if (bias1) bv += bias1[bn + c0 + j];
        if (bias2) bv += bias2[bn + c0 + j];
        #pragma unroll
        for (int i = 0; i < 4; ++i) {
            C[(size_t)(r0 + i) * N + bn + c0 + j] = acc[i][j] + bv;
        }
    }
}

// ---------------------------------------------------------------------------
__global__ void embed_k(const int* __restrict__ word, const float* __restrict__ emb,
                        float* __restrict__ x0)
{
    const int b = blockIdx.x, t = threadIdx.x;
    const int w = word[b];
    const float* src = emb + (size_t)w * H;
    float* dst = x0 + (size_t)b * H;
    for (int h = t; h < H; h += 256) dst[h] = src[h];
}

// gates[b][j], j in [0,4096): i=[0,H) f=[H,2H) g=[2H,3H) o=[3H,4H)
__global__ void lstm_cell_k(const float* __restrict__ gates, const float* __restrict__ c0,
                            float* __restrict__ h_out, float* __restrict__ c_out,
                            float* __restrict__ x_next)
{
    const int idx = blockIdx.x * 256 + threadIdx.x;   // < 128*1024
    const int b = idx >> 10, hh = idx & 1023;
    const float* g = gates + (size_t)b * (4 * H);
    const float gi = g[hh], gf = g[hh + H], gg = g[hh + 2 * H], go = g[hh + 3 * H];
    const float c = sigf(gf) * c0[idx] + sigf(gi) * tanhf(gg);
    const float h = sigf(go) * tanhf(c);
    c_out[idx] = c;
    h_out[idx] = h;
    x_next[idx] = h;
}

// attention position: p[b] = S*sigmoid(tanh(out @ w1^T + b1) @ w2^T + b2)
__global__ void attn_p_k(const float* __restrict__ x, const float* __restrict__ w1,
                         const float* __restrict__ b1, const float* __restrict__ w2,
                         const float* __restrict__ b2, const int* __restrict__ Sptr,
                         float* __restrict__ pb, int* __restrict__ wsi, int* __restrict__ wei)
{
    __shared__ float so[H];
    __shared__ float t1[512];
    __shared__ float red[256];
    const int b = blockIdx.x, t = threadIdx.x;
    for (int h = t; h < H; h += 256) so[h] = x[(size_t)b * H + h];
    __syncthreads();
    for (int k = t; k < 512; k += 256) {
        const float* wr = w1 + (size_t)k * H;
        float s = 0.f;
        for (int h = 0; h < H; ++h) s += so[h] * wr[h];
        t1[k] = tanhf(s + b1[k]);
    }
    __syncthreads();
    red[t] = t1[t] * w2[t] + t1[t + 256] * w2[t + 256];
    __syncthreads();
    for (int s = 128; s > 0; s >>= 1) {
        if (t < s) red[t] += red[t + s];
        __syncthreads();
    }
    if (t == 0) {
        const float S = (float)Sptr[0];
        const float sv = S * sigf(red[0] + b2[0]);
        pb[b]  = sv;
        wsi[b] = (int)rintf(fmaxf(sv - (float)WSZ, 0.f));
        wei[b] = (int)rintf(fminf(sv + (float)WSZ, S - 1.f));
    }
}

// window scores -> softmax*gauss -> a (out) and ctx
__global__ void attn_ctx_k(const float* __restrict__ x, const float* __restrict__ enc,
                           const float* __restrict__ pb, const int* __restrict__ wsi,
                           const int* __restrict__ wei,
                           float* __restrict__ a_out, float* __restrict__ ctx)
{
    __shared__ float so[H];
    __shared__ float swred[4][MAXW];
    __shared__ float ssc[MAXW];
    __shared__ float sa[MAXW];
    const int b = blockIdx.x, t = threadIdx.x;
    const int lane = t & 63, wv = t >> 6;
    for (int h = t; h < H; h += 256) so[h] = x[(size_t)b * H + h];
    const int w0 = wsi[b], w1e = wei[b];
    const float pbv = pb[b];
    __syncthreads();

    float ps[MAXW];
    #pragma unroll
    for (int w = 0; w < MAXW; ++w) ps[w] = 0.f;
    for (int h = t; h < H; h += 256) {
        const float o = so[h];
        #pragma unroll
        for (int w = 0; w < MAXW; ++w) {
            const int idx = w0 + w;
            if (idx <= w1e) ps[w] += o * enc[((size_t)idx * B + b) * H + h];
        }
    }
    #pragma unroll
    for (int w = 0; w < MAXW; ++w) {
        float v = ps[w];
        for (int off = 32; off > 0; off >>= 1) v += __shfl_down(v, off);
        if (lane == 0) swred[wv][w] = v;
    }
    __syncthreads();
    if (t == 0) {
        float m = -1e30f;
        for (int w = 0; w < MAXW; ++w) {
            const float s = swred[0][w] + swred[1][w] + swred[2][w] + swred[3][w];
            ssc[w] = s;
            m = fmaxf(m, s);
        }
        float den = 0.f;
        for (int w = 0; w < MAXW; ++w) den += expf(ssc[w] - m);
        for (int w = 0; w < MAXW; ++w) {
            const int idx = w0 + w;
            const float gauss = (idx <= w1e) ? expf(((float)idx - pbv) / 50.0f) : 0.f;
            sa[w] = expf(ssc[w] - m) / den * gauss;
        }
    }
    __syncthreads();
    if (t < MAXW) a_out[b * MAXW + t] = sa[t];
    for (int h = t; h < H; h += 256) {
        float acc = 0.f;
        #pragma unroll
        for (int w = 0; w < MAXW; ++w) {
            const int idx = w0 + w;
            if (idx <= w1e) acc += sa[w] * enc[((size_t)idx * B + b) * H + h];
        }
        ctx[(size_t)b * H + h] = acc;
    }
}

__global__ void tanh_k(float* __restrict__ p, int n)
{
    const int i = blockIdx.x * 256 + threadIdx.x;
    if (i < n) p[i] = tanhf(p[i]);
}

// per-row log_softmax over V, in place
__global__ void lsm_k(float* __restrict__ y)
{
    __shared__ float red[256];
    const int b = blockIdx.x, t = threadIdx.x;
    float* row = y + (size_t)b * V;
    float m = -1e30f;
    for (int v = t; v < V; v += 256) m = fmaxf(m, row[v]);
    red[t] = m; __syncthreads();
    for (int s = 128; s > 0; s >>= 1) {
        if (t < s) red[t] = fmaxf(red[t], red[t + s]);
        __syncthreads();
    }
    m = red[0]; __syncthreads();
    float sum = 0.f;
    for (int v = t; v < V; v += 256) sum += expf(row[v] - m);
    red[t] = sum; __syncthreads();
    for (int s = 128; s > 0; s >>= 1) {
        if (t < s) red[t] += red[t + s];
        __syncthreads();
    }
    const float lse = m + logf(red[0]);
    for (int v = t; v < V; v += 256) row[v] -= lse;
}

} // namespace

extern "C" void kernel_launch(void* const* d_in, const int* in_sizes, int n_in,
                              void* d_out, int out_size, void* d_ws, size_t ws_size,
                              hipStream_t stream)
{
    const int*   Sp   = (const int*)d_in[0];
    const float* enc  = (const float*)d_in[1];
    const int*   word = (const int*)d_in[2];
    const float* h0   = (const float*)d_in[3];
    const float* c0   = (const float*)d_in[4];
    const float* emb  = (const float*)d_in[5];
    const float* Wih  = (const float*)d_in[6];
    const float* Whh  = (const float*)d_in[7];
    const float* bih  = (const float*)d_in[8];
    const float* bhh  = (const float*)d_in[9];
    const float* aw1  = (const float*)d_in[10];
    const float* ab1  = (const float*)d_in[11];
    const float* aw2  = (const float*)d_in[12];
    const float* ab2  = (const float*)d_in[13];
    const float* f1w  = (const float*)d_in[14];
    const float* f1b  = (const float*)d_in[15];
    const float* f2w  = (const float*)d_in[16];
    const float* f2b  = (const float*)d_in[17];

    float* outp = (float*)d_out;
    float* y    = outp;                       // 128*32000
    float* o2   = y  + (size_t)B * V;         // 128*1024
    float* hN   = o2 + (size_t)B * H;         // 2*128*1024
    float* cN   = hN + 2 * (size_t)B * H;     // 2*128*1024
    float* aO   = cN + 2 * (size_t)B * H;     // 128*21

    float* wsf   = (float*)d_ws;
    float* x0    = wsf;                              // 128*1024
    float* gates = x0 + (size_t)B * H;               // 128*4096
    float* pbuf  = gates + (size_t)B * 4 * H;        // 128
    int*   wsi   = (int*)(pbuf + B);                 // 128
    int*   wei   = wsi + B;                          // 128
    float* ctx   = (float*)(wei + B);                // 128*1024

    embed_k<<<dim3(B), dim3(256), 0, stream>>>(word, emb, x0);

    for (int l = 0; l < 2; ++l) {
        gemm128<<<dim3(4 * H / 32), dim3(256), 0, stream>>>(
            x0, H, Wih + (size_t)l * 4 * H * H, H,
            h0 + (size_t)l * B * H, H, Whh + (size_t)l * 4 * H * H, H,
            bih + (size_t)l * 4 * H, bhh + (size_t)l * 4 * H,
            gates, 4 * H);
        lstm_cell_k<<<dim3(B * H / 256), dim3(256), 0, stream>>>(
            gates, c0 + (size_t)l * B * H,
            hN + (size_t)l * B * H, cN + (size_t)l * B * H, x0);
    }

    attn_p_k<<<dim3(B), dim3(256), 0, stream>>>(x0, aw1, ab1, aw2, ab2, Sp, pbuf, wsi, wei);
    attn_ctx_k<<<dim3(B), dim3(256), 0, stream>>>(x0, enc, pbuf, wsi, wei, aO, ctx);

    // fc1: cat([ctx, out]) @ fc1_w^T ; fc1_w is (1024, 2048) row-major
    gemm128<<<dim3(H / 32), dim3(256), 0, stream>>>(
        ctx, H, f1w, 2 * H,
        x0, H, f1w + H, 2 * H,
        f1b, nullptr, o2, H);
    tanh_k<<<dim3(B * H / 256), dim3(256), 0, stream>>>(o2, B * H);

    // fc2: o2 @ fc2_w^T -> logits directly into y region
    gemm128<<<dim3(V / 32), dim3(256), 0, stream>>>(
        o2, H, f2w, H,
        nullptr, 0, nullptr, 0,
        f2b, nullptr, y, V);

    lsm_k<<<dim3(B), dim3(256), 0, stream>>>(y);
}

// Round 4
// 346.880 us; speedup vs baseline: 2.0344x; 2.0344x over previous
//
#include <hip/hip_runtime.h>
#include <math.h>

namespace {

constexpr int B    = 128;
constexpr int H    = 1024;
constexpr int V    = 32000;
constexpr int WSZ  = 10;
constexpr int MAXW = 2 * WSZ + 1;   // 21

typedef __attribute__((ext_vector_type(8))) short bf16x8;
typedef __attribute__((ext_vector_type(4))) short short4v;
typedef __attribute__((ext_vector_type(4))) float f32x4;

__device__ __forceinline__ float sigf(float x) { return 1.0f / (1.0f + expf(-x)); }

__device__ __forceinline__ unsigned short rnebf(float f) {
    unsigned u = __float_as_uint(f);
    u += 0x7fffu + ((u >> 16) & 1u);
    return (unsigned short)(u >> 16);
}

struct S3 { short h, m, l; };

// exact 3-way truncation split: x == h + m + l + delta, |delta| <~ 2^-21 |x|,
// each part exactly representable in bf16.
__device__ __forceinline__ S3 split3(float x) {
    S3 r;
    const unsigned uh = __float_as_uint(x) & 0xFFFF0000u;
    const float fh = __uint_as_float(uh);
    const float r1 = x - fh;
    const unsigned um = __float_as_uint(r1) & 0xFFFF0000u;
    const float fm = __uint_as_float(um);
    const float r2 = r1 - fm;
    const unsigned ul = __float_as_uint(r2) & 0xFFFF0000u;
    r.h = (short)(uh >> 16);
    r.m = (short)(um >> 16);
    r.l = (short)(ul >> 16);
    return r;
}

// ---------------------------------------------------------------------------
// Plain bf16 MFMA GEMM (for fc1/fc2): out[y] = A_y[:,k0:k0+Ksz] @ W_y[:,wk0:+Ksz]^T
// ---------------------------------------------------------------------------
__global__ __launch_bounds__(256) void gemm_mfma(
    const short* __restrict__ A0, const short* __restrict__ A1,
    const float* __restrict__ W0, const float* __restrict__ W1,
    int ldw, int Ksz, int wk0m, int N,
    const float* __restrict__ bias, float* __restrict__ outbase)
{
    const int y = blockIdx.y;
    const short* A = (y & 2) ? A1 : A0;
    const float* W = (y & 2) ? W1 : W0;
    const int k0  = (y & 1) * Ksz;
    const int wk0 = (y & wk0m) * Ksz;
    float* out = outbase + (size_t)y * 128 * N;

    const int t    = threadIdx.x;
    const int lane = t & 63;
    const int w    = t >> 6;
    const int n0   = blockIdx.x * 64 + w * 16;
    const int m16  = lane & 15;
    const int ko8  = (lane >> 4) * 8;

    const float* wp = W + (size_t)(n0 + m16) * ldw + wk0 + ko8;
    const short* ap = A + (size_t)m16 * 1024 + k0 + ko8;

    f32x4 acc[8] = {};

    for (int kc = 0; kc < Ksz; kc += 32) {
        const f32x4 wa = *(const f32x4*)(wp);
        const f32x4 wb = *(const f32x4*)(wp + 4);
        bf16x8 bfr;
        bfr[0] = (short)rnebf(wa.x); bfr[1] = (short)rnebf(wa.y);
        bfr[2] = (short)rnebf(wa.z); bfr[3] = (short)rnebf(wa.w);
        bfr[4] = (short)rnebf(wb.x); bfr[5] = (short)rnebf(wb.y);
        bfr[6] = (short)rnebf(wb.z); bfr[7] = (short)rnebf(wb.w);
        #pragma unroll
        for (int m = 0; m < 8; ++m) {
            const bf16x8 afr = *(const bf16x8*)(ap + (size_t)m * 16 * 1024);
            acc[m] = __builtin_amdgcn_mfma_f32_16x16x32_bf16(afr, bfr, acc[m], 0, 0, 0);
        }
        wp += 32; ap += 32;
    }

    const int col = n0 + m16;
    const float bv = bias ? bias[col] : 0.0f;
    #pragma unroll
    for (int m = 0; m < 8; ++m) {
        const int rbase = m * 16 + (lane >> 4) * 4;
        #pragma unroll
        for (int r = 0; r < 4; ++r)
            out[(size_t)(rbase + r) * N + col] = acc[m][r] + bv;
    }
}

// ---------------------------------------------------------------------------
// Split-bf16 (near-fp32) MFMA GEMM for the LSTM gates.
// A is 128x1024 (3 bf16 split planes), W is 4096x1024 fp32, Ksz=512 per block
// (K-half by y&1), source pair by y&2. out = partial (summed later).
// ---------------------------------------------------------------------------
__global__ __launch_bounds__(256) void gemm_x3(
    const short* __restrict__ Ah0, const short* __restrict__ Am0, const short* __restrict__ Al0,
    const short* __restrict__ Ah1, const short* __restrict__ Am1, const short* __restrict__ Al1,
    const float* __restrict__ W0, const float* __restrict__ W1,
    float* __restrict__ outbase)
{
    const int y = blockIdx.y;
    const short* Ah = (y & 2) ? Ah1 : Ah0;
    const short* Am = (y & 2) ? Am1 : Am0;
    const short* Al = (y & 2) ? Al1 : Al0;
    const float* W  = (y & 2) ? W1  : W0;
    const int k0 = (y & 1) * 512;
    float* out = outbase + (size_t)y * 128 * 4096;

    const int t    = threadIdx.x;
    const int lane = t & 63;
    const int w    = t >> 6;
    const int n0   = blockIdx.x * 64 + w * 16;
    const int m16  = lane & 15;
    const int ko8  = (lane >> 4) * 8;

    const float* wp = W + (size_t)(n0 + m16) * 1024 + k0 + ko8;
    const size_t a0 = (size_t)m16 * 1024 + k0 + ko8;

    f32x4 acc[8] = {};

    for (int kc = 0; kc < 512; kc += 32) {
        const f32x4 wa = *(const f32x4*)(wp);
        const f32x4 wb = *(const f32x4*)(wp + 4);
        bf16x8 wh, wm, wl;
        #pragma unroll
        for (int j = 0; j < 4; ++j) {
            const S3 sa = split3(wa[j]);
            wh[j] = sa.h; wm[j] = sa.m; wl[j] = sa.l;
            const S3 sb = split3(wb[j]);
            wh[j + 4] = sb.h; wm[j + 4] = sb.m; wl[j + 4] = sb.l;
        }
        #pragma unroll
        for (int m = 0; m < 8; ++m) {
            const size_t ao = a0 + (size_t)m * 16 * 1024 + kc;
            const bf16x8 ah = *(const bf16x8*)(Ah + ao);
            const bf16x8 am = *(const bf16x8*)(Am + ao);
            const bf16x8 al = *(const bf16x8*)(Al + ao);
            acc[m] = __builtin_amdgcn_mfma_f32_16x16x32_bf16(ah, wh, acc[m], 0, 0, 0);
            acc[m] = __builtin_amdgcn_mfma_f32_16x16x32_bf16(ah, wm, acc[m], 0, 0, 0);
            acc[m] = __builtin_amdgcn_mfma_f32_16x16x32_bf16(am, wh, acc[m], 0, 0, 0);
            acc[m] = __builtin_amdgcn_mfma_f32_16x16x32_bf16(ah, wl, acc[m], 0, 0, 0);
            acc[m] = __builtin_amdgcn_mfma_f32_16x16x32_bf16(am, wm, acc[m], 0, 0, 0);
            acc[m] = __builtin_amdgcn_mfma_f32_16x16x32_bf16(al, wh, acc[m], 0, 0, 0);
        }
        wp += 32;
    }

    #pragma unroll
    for (int m = 0; m < 8; ++m) {
        const int rbase = m * 16 + (lane >> 4) * 4;
        #pragma unroll
        for (int r = 0; r < 4; ++r)
            out[(size_t)(rbase + r) * 4096 + n0 + m16] = acc[m][r];
    }
}

// ---------------------------------------------------------------------------
__global__ void embed_split_k(const int* __restrict__ word, const float* __restrict__ emb,
                              short* __restrict__ xh, short* __restrict__ xm,
                              short* __restrict__ xl)
{
    const int b = blockIdx.x, t = threadIdx.x;
    const int w = word[b];
    const float4 v = ((const float4*)(emb + (size_t)w * H))[t];
    short4v sh, sm, sl;
    S3 s;
    s = split3(v.x); sh.x = s.h; sm.x = s.m; sl.x = s.l;
    s = split3(v.y); sh.y = s.h; sm.y = s.m; sl.y = s.l;
    s = split3(v.z); sh.z = s.h; sm.z = s.m; sl.z = s.l;
    s = split3(v.w); sh.w = s.h; sm.w = s.m; sl.w = s.l;
    const size_t o = (size_t)b * H + t * 4;
    *(short4v*)(xh + o) = sh;
    *(short4v*)(xm + o) = sm;
    *(short4v*)(xl + o) = sl;
}

__global__ void split3_k(const float* __restrict__ in, short* __restrict__ oh,
                         short* __restrict__ om, short* __restrict__ ol)
{
    const int i = blockIdx.x * 256 + threadIdx.x;
    const float4 v = ((const float4*)in)[i];
    short4v sh, sm, sl;
    S3 s;
    s = split3(v.x); sh.x = s.h; sm.x = s.m; sl.x = s.l;
    s = split3(v.y); sh.y = s.h; sm.y = s.m; sl.y = s.l;
    s = split3(v.z); sh.z = s.h; sm.z = s.m; sl.z = s.l;
    s = split3(v.w); sh.w = s.h; sm.w = s.m; sl.w = s.l;
    ((short4v*)oh)[i] = sh;
    ((short4v*)om)[i] = sm;
    ((short4v*)ol)[i] = sl;
}

// sum 4 partials + biases -> LSTM cell -> h (fp32), c (fp32), x splits (bf16)
__global__ void lstm_cell_k(const float* __restrict__ part,
                            const float* __restrict__ bih, const float* __restrict__ bhh,
                            const float* __restrict__ c0,
                            float* __restrict__ h_out, float* __restrict__ c_out,
                            short* __restrict__ xh, short* __restrict__ xm,
                            short* __restrict__ xl)
{
    const int idx = blockIdx.x * 256 + threadIdx.x;   // < 128*1024
    const int b = idx >> 10, hh = idx & 1023;
    const size_t base = (size_t)b * 4096;
    const float* p0 = part + base;
    const float* p1 = p0 + 128 * 4096;
    const float* p2 = p1 + 128 * 4096;
    const float* p3 = p2 + 128 * 4096;
    float g[4];
    #pragma unroll
    for (int j = 0; j < 4; ++j) {
        const int o = hh + j * H;
        g[j] = p0[o] + p1[o] + p2[o] + p3[o] + bih[o] + bhh[o];
    }
    const float c = sigf(g[1]) * c0[idx] + sigf(g[0]) * tanhf(g[2]);
    const float h = sigf(g[3]) * tanhf(c);
    c_out[idx] = c;
    h_out[idx] = h;
    const S3 s = split3(h);
    xh[idx] = s.h; xm[idx] = s.m; xl[idx] = s.l;
}

// attention position: p[b] = S*sigmoid(tanh(x @ w1^T + b1) @ w2^T + b2)
__global__ void attn_p_k(const float* __restrict__ x, const float* __restrict__ w1,
                         const float* __restrict__ b1, const float* __restrict__ w2,
                         const float* __restrict__ b2, const int* __restrict__ Sptr,
                         float* __restrict__ pb, int* __restrict__ wsi, int* __restrict__ wei)
{
    __shared__ float so[H];
    __shared__ float t1[512];
    __shared__ float red[256];
    const int b = blockIdx.x, t = threadIdx.x;
    for (int h = t; h < H; h += 256) so[h] = x[(size_t)b * H + h];
    __syncthreads();
    for (int k = t; k < 512; k += 256) {
        const float* wr = w1 + (size_t)k * H;
        float s = 0.f;
        #pragma unroll 4
        for (int h = 0; h < H; ++h) s += so[h] * wr[h];
        t1[k] = tanhf(s + b1[k]);
    }
    __syncthreads();
    red[t] = t1[t] * w2[t] + t1[t + 256] * w2[t + 256];
    __syncthreads();
    for (int s = 128; s > 0; s >>= 1) {
        if (t < s) red[t] += red[t + s];
        __syncthreads();
    }
    if (t == 0) {
        const float S = (float)Sptr[0];
        const float sv = S * sigf(red[0] + b2[0]);
        pb[b]  = sv;
        wsi[b] = (int)rintf(fmaxf(sv - (float)WSZ, 0.f));
        wei[b] = (int)rintf(fminf(sv + (float)WSZ, S - 1.f));
    }
}

// window scores -> softmax*gauss -> a (out) and ctx (bf16)
__global__ void attn_ctx_k(const float* __restrict__ x, const float* __restrict__ enc,
                           const float* __restrict__ pb, const int* __restrict__ wsi,
                           const int* __restrict__ wei,
                           float* __restrict__ a_out, short* __restrict__ ctxb)
{
    __shared__ float so[H];
    __shared__ float swred[4][MAXW];
    __shared__ float ssc[MAXW];
    __shared__ float sa[MAXW];
    const int b = blockIdx.x, t = threadIdx.x;
    const int lane = t & 63, wv = t >> 6;
    for (int h = t; h < H; h += 256) so[h] = x[(size_t)b * H + h];
    const int w0 = wsi[b], w1e = wei[b];
    const float pbv = pb[b];
    __syncthreads();

    float ps[MAXW];
    #pragma unroll
    for (int w = 0; w < MAXW; ++w) ps[w] = 0.f;
    for (int h4 = t; h4 < H / 4; h4 += 256) {
        const float4 o = ((const float4*)so)[h4];
        #pragma unroll
        for (int w = 0; w < MAXW; ++w) {
            const int idx = w0 + w;
            if (idx <= w1e) {
                const float4 e = *(const float4*)(enc + ((size_t)idx * B + b) * H + h4 * 4);
                ps[w] += o.x * e.x + o.y * e.y + o.z * e.z + o.w * e.w;
            }
        }
    }
    #pragma unroll
    for (int w = 0; w < MAXW; ++w) {
        float v = ps[w];
        for (int off = 32; off > 0; off >>= 1) v += __shfl_down(v, off);
        if (lane == 0) swred[wv][w] = v;
    }
    __syncthreads();
    if (t == 0) {
        float m = -1e30f;
        for (int w = 0; w < MAXW; ++w) {
            const float s = swred[0][w] + swred[1][w] + swred[2][w] + swred[3][w];
            ssc[w] = s;
            m = fmaxf(m, s);
        }
        float den = 0.f;
        for (int w = 0; w < MAXW; ++w) den += expf(ssc[w] - m);
        for (int w = 0; w < MAXW; ++w) {
            const int idx = w0 + w;
            const float gauss = (idx <= w1e) ? expf(((float)idx - pbv) / 50.0f) : 0.f;
            sa[w] = expf(ssc[w] - m) / den * gauss;
        }
    }
    __syncthreads();
    if (t < MAXW) a_out[b * MAXW + t] = sa[t];
    for (int h4 = t; h4 < H / 4; h4 += 256) {
        float4 acc = {0.f, 0.f, 0.f, 0.f};
        #pragma unroll
        for (int w = 0; w < MAXW; ++w) {
            const int idx = w0 + w;
            if (idx <= w1e) {
                const float4 e = *(const float4*)(enc + ((size_t)idx * B + b) * H + h4 * 4);
                acc.x += sa[w] * e.x; acc.y += sa[w] * e.y;
                acc.z += sa[w] * e.z; acc.w += sa[w] * e.w;
            }
        }
        short4v s;
        s.x = (short)rnebf(acc.x); s.y = (short)rnebf(acc.y);
        s.z = (short)rnebf(acc.z); s.w = (short)rnebf(acc.w);
        *(short4v*)(ctxb + (size_t)b * H + h4 * 4) = s;
    }
}

// sum 4 fc1 partials + bias -> tanh -> o2 (fp32, d_out) + o2b (bf16)
__global__ void fc1_fin_k(const float* __restrict__ part, const float* __restrict__ bias,
                          float* __restrict__ o2, short* __restrict__ o2b)
{
    const int idx = blockIdx.x * 256 + threadIdx.x;   // < 128*1024
    const int n = idx & 1023;
    const float v = tanhf(part[idx] + part[idx + 131072] + part[idx + 2 * 131072] +
                          part[idx + 3 * 131072] + bias[n]);
    o2[idx] = v;
    o2b[idx] = (short)rnebf(v);
}

// in-place log_softmax per row over V
__global__ __launch_bounds__(1024) void lsm_k(float* __restrict__ y)
{
    __shared__ float sm[16], ss[16], slse;
    const int b = blockIdx.x, t = threadIdx.x;
    float* row = y + (size_t)b * V;
    float m = -1e30f, s = 0.f;
    for (int v4 = t; v4 < V / 4; v4 += 1024) {
        const float4 x = ((const float4*)row)[v4];
        const float mm = fmaxf(fmaxf(x.x, x.y), fmaxf(x.z, x.w));
        if (mm > m) { s *= expf(m - mm); m = mm; }
        s += expf(x.x - m) + expf(x.y - m) + expf(x.z - m) + expf(x.w - m);
    }
    for (int off = 32; off > 0; off >>= 1) {
        const float mo = __shfl_down(m, off), so = __shfl_down(s, off);
        const float mn = fmaxf(m, mo);
        s = s * expf(m - mn) + so * expf(mo - mn);
        m = mn;
    }
    const int wv = t >> 6, lane = t & 63;
    if (lane == 0) { sm[wv] = m; ss[wv] = s; }
    __syncthreads();
    if (t == 0) {
        float M = sm[0], S = ss[0];
        for (int i = 1; i < 16; ++i) {
            const float mn = fmaxf(M, sm[i]);
            S = S * expf(M - mn) + ss[i] * expf(sm[i] - mn);
            M = mn;
        }
        slse = M + logf(S);
    }
    __syncthreads();
    const float lse = slse;
    for (int v4 = t; v4 < V / 4; v4 += 1024) {
        float4 x = ((const float4*)row)[v4];
        x.x -= lse; x.y -= lse; x.z -= lse; x.w -= lse;
        ((float4*)row)[v4] = x;
    }
}

} // namespace

extern "C" void kernel_launch(void* const* d_in, const int* in_sizes, int n_in,
                              void* d_out, int out_size, void* d_ws, size_t ws_size,
                              hipStream_t stream)
{
    const int*   Sp   = (const int*)d_in[0];
    const float* enc  = (const float*)d_in[1];
    const int*   word = (const int*)d_in[2];
    const float* h0   = (const float*)d_in[3];
    const float* c0   = (const float*)d_in[4];
    const float* emb  = (const float*)d_in[5];
    const float* Wih  = (const float*)d_in[6];
    const float* Whh  = (const float*)d_in[7];
    const float* bih  = (const float*)d_in[8];
    const float* bhh  = (const float*)d_in[9];
    const float* aw1  = (const float*)d_in[10];
    const float* ab1  = (const float*)d_in[11];
    const float* aw2  = (const float*)d_in[12];
    const float* ab2  = (const float*)d_in[13];
    const float* f1w  = (const float*)d_in[14];
    const float* f1b  = (const float*)d_in[15];
    const float* f2w  = (const float*)d_in[16];
    const float* f2b  = (const float*)d_in[17];

    float* outp = (float*)d_out;
    float* y    = outp;                       // 128*32000
    float* o2   = y  + (size_t)B * V;         // 128*1024
    float* hN   = o2 + (size_t)B * H;         // 2*128*1024
    float* cN   = hN + 2 * (size_t)B * H;     // 2*128*1024
    float* aO   = cN + 2 * (size_t)B * H;     // 128*21

    char* wsp = (char*)d_ws;
    short* xh   = (short*)wsp;  wsp += (size_t)B * H * 2;
    short* xm   = (short*)wsp;  wsp += (size_t)B * H * 2;
    short* xl   = (short*)wsp;  wsp += (size_t)B * H * 2;
    short* h0h  = (short*)wsp;  wsp += (size_t)2 * B * H * 2;
    short* h0m  = (short*)wsp;  wsp += (size_t)2 * B * H * 2;
    short* h0l  = (short*)wsp;  wsp += (size_t)2 * B * H * 2;
    short* ctxb = (short*)wsp;  wsp += (size_t)B * H * 2;
    short* o2b  = (short*)wsp;  wsp += (size_t)B * H * 2;
    float* part = (float*)wsp;  wsp += (size_t)4 * B * 4 * H * 4;  // 8 MB
    float* pbuf = (float*)wsp;  wsp += B * 4;
    int*   wsi  = (int*)wsp;    wsp += B * 4;
    int*   wei  = (int*)wsp;    wsp += B * 4;

    embed_split_k<<<dim3(B), dim3(256), 0, stream>>>(word, emb, xh, xm, xl);
    split3_k<<<dim3(2 * B * H / 1024), dim3(256), 0, stream>>>(h0, h0h, h0m, h0l);

    for (int l = 0; l < 2; ++l) {
        gemm_x3<<<dim3(4 * H / 64, 4), dim3(256), 0, stream>>>(
            xh, xm, xl,
            h0h + (size_t)l * B * H, h0m + (size_t)l * B * H, h0l + (size_t)l * B * H,
            Wih + (size_t)l * 4 * H * H, Whh + (size_t)l * 4 * H * H,
            part);
        lstm_cell_k<<<dim3(B * H / 256), dim3(256), 0, stream>>>(
            part, bih + (size_t)l * 4 * H, bhh + (size_t)l * 4 * H,
            c0 + (size_t)l * B * H,
            hN + (size_t)l * B * H, cN + (size_t)l * B * H, xh, xm, xl);
    }

    const float* hfin = hN + (size_t)B * H;  // last layer h (fp32)
    attn_p_k<<<dim3(B), dim3(256), 0, stream>>>(hfin, aw1, ab1, aw2, ab2, Sp, pbuf, wsi, wei);
    attn_ctx_k<<<dim3(B), dim3(256), 0, stream>>>(hfin, enc, pbuf, wsi, wei, aO, ctxb);

    // fc1: [ctx | out] @ f1w^T, f1w (1024 x 2048) -> 4 split-K partials
    gemm_mfma<<<dim3(H / 64, 4), dim3(256), 0, stream>>>(
        ctxb, xh, f1w, f1w, 2 * H, 512, 3, H, nullptr, part);
    fc1_fin_k<<<dim3(B * H / 256), dim3(256), 0, stream>>>(part, f1b, o2, o2b);

    // fc2: o2 @ f2w^T + b -> logits straight into y
    gemm_mfma<<<dim3(V / 64, 1), dim3(256), 0, stream>>>(
        o2b, o2b, f2w, f2w, H, H, 0, V, f2b, y);

    lsm_k<<<dim3(B), dim3(1024), 0, stream>>>(y);
}

// Round 5
// 284.122 us; speedup vs baseline: 2.4838x; 1.2209x over previous
//
#include <hip/hip_runtime.h>
#include <math.h>

namespace {

constexpr int B    = 128;
constexpr int H    = 1024;
constexpr int V    = 32000;
constexpr int WSZ  = 10;
constexpr int MAXW = 2 * WSZ + 1;   // 21

typedef __attribute__((ext_vector_type(8))) short bf16x8;
typedef __attribute__((ext_vector_type(4))) short short4v;
typedef __attribute__((ext_vector_type(4))) float f32x4;

__device__ __forceinline__ float sigf(float x) { return 1.0f / (1.0f + expf(-x)); }

__device__ __forceinline__ unsigned short rnebf(float f) {
    unsigned u = __float_as_uint(f);
    u += 0x7fffu + ((u >> 16) & 1u);
    return (unsigned short)(u >> 16);
}

__device__ __forceinline__ bf16x8 cvt8(const f32x4 a, const f32x4 b) {
    bf16x8 r;
    r[0] = (short)rnebf(a.x); r[1] = (short)rnebf(a.y);
    r[2] = (short)rnebf(a.z); r[3] = (short)rnebf(a.w);
    r[4] = (short)rnebf(b.x); r[5] = (short)rnebf(b.y);
    r[6] = (short)rnebf(b.z); r[7] = (short)rnebf(b.w);
    return r;
}

struct S3 { short h, m, l; };

// exact 3-way truncation split: x == h + m + l + delta, |delta| <~ 2^-21 |x|
__device__ __forceinline__ S3 split3(float x) {
    S3 r;
    const unsigned uh = __float_as_uint(x) & 0xFFFF0000u;
    const float fh = __uint_as_float(uh);
    const float r1 = x - fh;
    const unsigned um = __float_as_uint(r1) & 0xFFFF0000u;
    const float fm = __uint_as_float(um);
    const float r2 = r1 - fm;
    const unsigned ul = __float_as_uint(r2) & 0xFFFF0000u;
    r.h = (short)(uh >> 16);
    r.m = (short)(um >> 16);
    r.l = (short)(ul >> 16);
    return r;
}

__device__ __forceinline__ void split8(const f32x4 a, const f32x4 b,
                                       bf16x8& wh, bf16x8& wm, bf16x8& wl) {
    S3 s;
    s = split3(a.x); wh[0] = s.h; wm[0] = s.m; wl[0] = s.l;
    s = split3(a.y); wh[1] = s.h; wm[1] = s.m; wl[1] = s.l;
    s = split3(a.z); wh[2] = s.h; wm[2] = s.m; wl[2] = s.l;
    s = split3(a.w); wh[3] = s.h; wm[3] = s.m; wl[3] = s.l;
    s = split3(b.x); wh[4] = s.h; wm[4] = s.m; wl[4] = s.l;
    s = split3(b.y); wh[5] = s.h; wm[5] = s.m; wl[5] = s.l;
    s = split3(b.z); wh[6] = s.h; wm[6] = s.m; wl[6] = s.l;
    s = split3(b.w); wh[7] = s.h; wm[7] = s.m; wl[7] = s.l;
}

// ---------------------------------------------------------------------------
// fc2: out[128 x 32000] = A(bf16 128x1024) @ W(f32 32000x1024)^T + bias
// 256 thr = 4 waves; wave handles 32 cols (2 MFMA col-tiles sharing A frags).
// 1-deep register prefetch of W and A per 32-k chunk. Grid 250 blocks.
// ---------------------------------------------------------------------------
__global__ __launch_bounds__(256) void fc2_gemm(
    const short* __restrict__ A, const float* __restrict__ W,
    const float* __restrict__ bias, float* __restrict__ out)
{
    const int t = threadIdx.x;
    const int lane = t & 63;
    const int wv = t >> 6;
    const int n0 = blockIdx.x * 128 + wv * 32;
    const int m16 = lane & 15;
    const int ko8 = (lane >> 4) * 8;

    const float* wp0 = W + (size_t)(n0 + m16) * 1024 + ko8;
    const float* wp1 = W + (size_t)(n0 + 16 + m16) * 1024 + ko8;
    const short* ap  = A + (size_t)m16 * 1024 + ko8;

    f32x4 acc0[8] = {}, acc1[8] = {};

    f32x4 c0a = *(const f32x4*)(wp0);
    f32x4 c0b = *(const f32x4*)(wp0 + 4);
    f32x4 c1a = *(const f32x4*)(wp1);
    f32x4 c1b = *(const f32x4*)(wp1 + 4);
    bf16x8 ca[8];
    #pragma unroll
    for (int m = 0; m < 8; ++m) ca[m] = *(const bf16x8*)(ap + (size_t)m * 16 * 1024);

    for (int kc = 0; kc < 1024 - 32; kc += 32) {
        const int kn = kc + 32;
        const f32x4 n0a = *(const f32x4*)(wp0 + kn);
        const f32x4 n0b = *(const f32x4*)(wp0 + kn + 4);
        const f32x4 n1a = *(const f32x4*)(wp1 + kn);
        const f32x4 n1b = *(const f32x4*)(wp1 + kn + 4);
        bf16x8 na[8];
        #pragma unroll
        for (int m = 0; m < 8; ++m)
            na[m] = *(const bf16x8*)(ap + (size_t)m * 16 * 1024 + kn);

        const bf16x8 b0 = cvt8(c0a, c0b);
        const bf16x8 b1 = cvt8(c1a, c1b);
        #pragma unroll
        for (int m = 0; m < 8; ++m) {
            acc0[m] = __builtin_amdgcn_mfma_f32_16x16x32_bf16(ca[m], b0, acc0[m], 0, 0, 0);
            acc1[m] = __builtin_amdgcn_mfma_f32_16x16x32_bf16(ca[m], b1, acc1[m], 0, 0, 0);
        }
        c0a = n0a; c0b = n0b; c1a = n1a; c1b = n1b;
        #pragma unroll
        for (int m = 0; m < 8; ++m) ca[m] = na[m];
    }
    {   // tail chunk
        const bf16x8 b0 = cvt8(c0a, c0b);
        const bf16x8 b1 = cvt8(c1a, c1b);
        #pragma unroll
        for (int m = 0; m < 8; ++m) {
            acc0[m] = __builtin_amdgcn_mfma_f32_16x16x32_bf16(ca[m], b0, acc0[m], 0, 0, 0);
            acc1[m] = __builtin_amdgcn_mfma_f32_16x16x32_bf16(ca[m], b1, acc1[m], 0, 0, 0);
        }
    }

    const float bv0 = bias[n0 + m16];
    const float bv1 = bias[n0 + 16 + m16];
    #pragma unroll
    for (int m = 0; m < 8; ++m) {
        const int rbase = m * 16 + (lane >> 4) * 4;
        #pragma unroll
        for (int r = 0; r < 4; ++r) {
            out[(size_t)(rbase + r) * V + n0 + m16]      = acc0[m][r] + bv0;
            out[(size_t)(rbase + r) * V + n0 + 16 + m16] = acc1[m][r] + bv1;
        }
    }
}

// ---------------------------------------------------------------------------
// Split-bf16 (near-fp32) MFMA GEMM. A: 128x1024 in 3 bf16 planes (row stride
// 1024). W: fp32, row stride 1024. Per block: Ksz=512 chunk of K selected by
// y&1; source pair by y>>1. out = partial y at outbase + y*128*N.
// Used for LSTM gates (N=4096, grid (64,4)) and attn t1-pre (N=512, grid (8,2)).
// ---------------------------------------------------------------------------
__global__ __launch_bounds__(256) void gemm_x3(
    const short* __restrict__ Ah0, const short* __restrict__ Am0, const short* __restrict__ Al0,
    const short* __restrict__ Ah1, const short* __restrict__ Am1, const short* __restrict__ Al1,
    const float* __restrict__ W0, const float* __restrict__ W1,
    int N, float* __restrict__ outbase)
{
    const int y = blockIdx.y;
    const int src = y >> 1;
    const short* Ah = src ? Ah1 : Ah0;
    const short* Am = src ? Am1 : Am0;
    const short* Al = src ? Al1 : Al0;
    const float* W  = src ? W1  : W0;
    const int k0 = (y & 1) * 512;
    float* out = outbase + (size_t)y * 128 * N;

    const int t    = threadIdx.x;
    const int lane = t & 63;
    const int wv   = t >> 6;
    const int n0   = blockIdx.x * 64 + wv * 16;
    const int m16  = lane & 15;
    const int ko8  = (lane >> 4) * 8;

    const float* wp = W + (size_t)(n0 + m16) * 1024 + k0 + ko8;
    const size_t a0 = (size_t)m16 * 1024 + k0 + ko8;

    f32x4 acc[8] = {};

    f32x4 cwa = *(const f32x4*)(wp);
    f32x4 cwb = *(const f32x4*)(wp + 4);

    for (int kc = 0; kc < 512; kc += 32) {
        f32x4 nwa, nwb;
        if (kc + 32 < 512) {
            nwa = *(const f32x4*)(wp + kc + 32);
            nwb = *(const f32x4*)(wp + kc + 36);
        }
        bf16x8 wh, wm, wl;
        split8(cwa, cwb, wh, wm, wl);
        #pragma unroll
        for (int m = 0; m < 8; ++m) {
            const size_t ao = a0 + (size_t)m * 16 * 1024 + kc;
            const bf16x8 ah = *(const bf16x8*)(Ah + ao);
            const bf16x8 am = *(const bf16x8*)(Am + ao);
            const bf16x8 al = *(const bf16x8*)(Al + ao);
            acc[m] = __builtin_amdgcn_mfma_f32_16x16x32_bf16(ah, wh, acc[m], 0, 0, 0);
            acc[m] = __builtin_amdgcn_mfma_f32_16x16x32_bf16(ah, wm, acc[m], 0, 0, 0);
            acc[m] = __builtin_amdgcn_mfma_f32_16x16x32_bf16(am, wh, acc[m], 0, 0, 0);
            acc[m] = __builtin_amdgcn_mfma_f32_16x16x32_bf16(ah, wl, acc[m], 0, 0, 0);
            acc[m] = __builtin_amdgcn_mfma_f32_16x16x32_bf16(am, wm, acc[m], 0, 0, 0);
            acc[m] = __builtin_amdgcn_mfma_f32_16x16x32_bf16(al, wh, acc[m], 0, 0, 0);
        }
        cwa = nwa; cwb = nwb;
    }

    #pragma unroll
    for (int m = 0; m < 8; ++m) {
        const int rbase = m * 16 + (lane >> 4) * 4;
        #pragma unroll
        for (int r = 0; r < 4; ++r)
            out[(size_t)(rbase + r) * N + n0 + m16] = acc[m][r];
    }
}

// ---------------------------------------------------------------------------
// fc1: 8-way split-K partials. y in [0,8): src=y>>2 (A0=ctx cols 0-1023,
// A1=out cols 1024-2047 of f1w), k0=(y&3)*256. W row stride 2048.
// ---------------------------------------------------------------------------
__global__ __launch_bounds__(256) void fc1_gemm(
    const short* __restrict__ A0, const short* __restrict__ A1,
    const float* __restrict__ W, float* __restrict__ outbase)
{
    const int y = blockIdx.y;
    const int src = y >> 2;
    const short* A = src ? A1 : A0;
    const int k0 = (y & 3) * 256;
    const int wk0 = src * 1024 + k0;
    float* out = outbase + (size_t)y * 128 * 1024;

    const int t    = threadIdx.x;
    const int lane = t & 63;
    const int wv   = t >> 6;
    const int n0   = blockIdx.x * 64 + wv * 16;
    const int m16  = lane & 15;
    const int ko8  = (lane >> 4) * 8;

    const float* wp = W + (size_t)(n0 + m16) * 2048 + wk0 + ko8;
    const short* ap = A + (size_t)m16 * 1024 + k0 + ko8;

    f32x4 acc[8] = {};
    f32x4 cwa = *(const f32x4*)(wp);
    f32x4 cwb = *(const f32x4*)(wp + 4);

    for (int kc = 0; kc < 256; kc += 32) {
        f32x4 nwa, nwb;
        if (kc + 32 < 256) {
            nwa = *(const f32x4*)(wp + kc + 32);
            nwb = *(const f32x4*)(wp + kc + 36);
        }
        const bf16x8 bfr = cvt8(cwa, cwb);
        #pragma unroll
        for (int m = 0; m < 8; ++m) {
            const bf16x8 afr = *(const bf16x8*)(ap + (size_t)m * 16 * 1024 + kc);
            acc[m] = __builtin_amdgcn_mfma_f32_16x16x32_bf16(afr, bfr, acc[m], 0, 0, 0);
        }
        cwa = nwa; cwb = nwb;
    }

    #pragma unroll
    for (int m = 0; m < 8; ++m) {
        const int rbase = m * 16 + (lane >> 4) * 4;
        #pragma unroll
        for (int r = 0; r < 4; ++r)
            out[(size_t)(rbase + r) * 1024 + n0 + m16] = acc[m][r];
    }
}

// ---------------------------------------------------------------------------
__global__ void embed_split_k(const int* __restrict__ word, const float* __restrict__ emb,
                              short* __restrict__ xh, short* __restrict__ xm,
                              short* __restrict__ xl)
{
    const int b = blockIdx.x, t = threadIdx.x;
    const int w = word[b];
    const float4 v = ((const float4*)(emb + (size_t)w * H))[t];
    short4v sh, sm, sl;
    S3 s;
    s = split3(v.x); sh.x = s.h; sm.x = s.m; sl.x = s.l;
    s = split3(v.y); sh.y = s.h; sm.y = s.m; sl.y = s.l;
    s = split3(v.z); sh.z = s.h; sm.z = s.m; sl.z = s.l;
    s = split3(v.w); sh.w = s.h; sm.w = s.m; sl.w = s.l;
    const size_t o = (size_t)b * H + t * 4;
    *(short4v*)(xh + o) = sh;
    *(short4v*)(xm + o) = sm;
    *(short4v*)(xl + o) = sl;
}

__global__ void split3_k(const float* __restrict__ in, short* __restrict__ oh,
                         short* __restrict__ om, short* __restrict__ ol)
{
    const int i = blockIdx.x * 256 + threadIdx.x;
    const float4 v = ((const float4*)in)[i];
    short4v sh, sm, sl;
    S3 s;
    s = split3(v.x); sh.x = s.h; sm.x = s.m; sl.x = s.l;
    s = split3(v.y); sh.y = s.h; sm.y = s.m; sl.y = s.l;
    s = split3(v.z); sh.z = s.h; sm.z = s.m; sl.z = s.l;
    s = split3(v.w); sh.w = s.h; sm.w = s.m; sl.w = s.l;
    ((short4v*)oh)[i] = sh;
    ((short4v*)om)[i] = sm;
    ((short4v*)ol)[i] = sl;
}

// sum 4 partials + biases -> LSTM cell -> h (fp32), c (fp32), x splits (bf16)
__global__ void lstm_cell_k(const float* __restrict__ part,
                            const float* __restrict__ bih, const float* __restrict__ bhh,
                            const float* __restrict__ c0,
                            float* __restrict__ h_out, float* __restrict__ c_out,
                            short* __restrict__ xh, short* __restrict__ xm,
                            short* __restrict__ xl)
{
    const int idx = blockIdx.x * 256 + threadIdx.x;   // < 128*1024
    const int b = idx >> 10, hh = idx & 1023;
    const size_t base = (size_t)b * 4096;
    const float* p0 = part + base;
    const float* p1 = p0 + 128 * 4096;
    const float* p2 = p1 + 128 * 4096;
    const float* p3 = p2 + 128 * 4096;
    float g[4];
    #pragma unroll
    for (int j = 0; j < 4; ++j) {
        const int o = hh + j * H;
        g[j] = p0[o] + p1[o] + p2[o] + p3[o] + bih[o] + bhh[o];
    }
    const float c = sigf(g[1]) * c0[idx] + sigf(g[0]) * tanhf(g[2]);
    const float h = sigf(g[3]) * tanhf(c);
    c_out[idx] = c;
    h_out[idx] = h;
    const S3 s = split3(h);
    xh[idx] = s.h; xm[idx] = s.m; xl[idx] = s.l;
}

// finish attention-position: sum 2 t1-pre partials, tanh, dot w2, sigmoid -> p/ws/we
__global__ void attn_fin_k(const float* __restrict__ part, const float* __restrict__ b1,
                           const float* __restrict__ w2, const float* __restrict__ b2,
                           const int* __restrict__ Sptr,
                           float* __restrict__ pb, int* __restrict__ wsi, int* __restrict__ wei)
{
    __shared__ float red[256];
    const int b = blockIdx.x, t = threadIdx.x;
    const float* pa = part + (size_t)b * 512;
    const float* pbq = part + 128 * 512 + (size_t)b * 512;
    const float v0 = tanhf(pa[t]       + pbq[t]       + b1[t])       * w2[t];
    const float v1 = tanhf(pa[t + 256] + pbq[t + 256] + b1[t + 256]) * w2[t + 256];
    red[t] = v0 + v1;
    __syncthreads();
    for (int s = 128; s > 0; s >>= 1) {
        if (t < s) red[t] += red[t + s];
        __syncthreads();
    }
    if (t == 0) {
        const float S = (float)Sptr[0];
        const float sv = S * sigf(red[0] + b2[0]);
        pb[b]  = sv;
        wsi[b] = (int)rintf(fmaxf(sv - (float)WSZ, 0.f));
        wei[b] = (int)rintf(fminf(sv + (float)WSZ, S - 1.f));
    }
}

// window scores -> softmax*gauss -> a (out) and ctx (bf16)
__global__ void attn_ctx_k(const float* __restrict__ x, const float* __restrict__ enc,
                           const float* __restrict__ pb, const int* __restrict__ wsi,
                           const int* __restrict__ wei,
                           float* __restrict__ a_out, short* __restrict__ ctxb)
{
    __shared__ float so[H];
    __shared__ float swred[4][MAXW];
    __shared__ float ssc[MAXW];
    __shared__ float sa[MAXW];
    const int b = blockIdx.x, t = threadIdx.x;
    const int lane = t & 63, wv = t >> 6;
    for (int h = t; h < H; h += 256) so[h] = x[(size_t)b * H + h];
    const int w0 = wsi[b], w1e = wei[b];
    const float pbv = pb[b];
    __syncthreads();

    float ps[MAXW];
    #pragma unroll
    for (int w = 0; w < MAXW; ++w) ps[w] = 0.f;
    for (int h4 = t; h4 < H / 4; h4 += 256) {
        const float4 o = ((const float4*)so)[h4];
        #pragma unroll
        for (int w = 0; w < MAXW; ++w) {
            const int idx = w0 + w;
            if (idx <= w1e) {
                const float4 e = *(const float4*)(enc + ((size_t)idx * B + b) * H + h4 * 4);
                ps[w] += o.x * e.x + o.y * e.y + o.z * e.z + o.w * e.w;
            }
        }
    }
    #pragma unroll
    for (int w = 0; w < MAXW; ++w) {
        float v = ps[w];
        for (int off = 32; off > 0; off >>= 1) v += __shfl_down(v, off);
        if (lane == 0) swred[wv][w] = v;
    }
    __syncthreads();
    if (t == 0) {
        float m = -1e30f;
        for (int w = 0; w < MAXW; ++w) {
            const float s = swred[0][w] + swred[1][w] + swred[2][w] + swred[3][w];
            ssc[w] = s;
            m = fmaxf(m, s);
        }
        float den = 0.f;
        for (int w = 0; w < MAXW; ++w) den += expf(ssc[w] - m);
        for (int w = 0; w < MAXW; ++w) {
            const int idx = w0 + w;
            const float gauss = (idx <= w1e) ? expf(((float)idx - pbv) / 50.0f) : 0.f;
            sa[w] = expf(ssc[w] - m) / den * gauss;
        }
    }
    __syncthreads();
    if (t < MAXW) a_out[b * MAXW + t] = sa[t];
    for (int h4 = t; h4 < H / 4; h4 += 256) {
        float4 acc = {0.f, 0.f, 0.f, 0.f};
        #pragma unroll
        for (int w = 0; w < MAXW; ++w) {
            const int idx = w0 + w;
            if (idx <= w1e) {
                const float4 e = *(const float4*)(enc + ((size_t)idx * B + b) * H + h4 * 4);
                acc.x += sa[w] * e.x; acc.y += sa[w] * e.y;
                acc.z += sa[w] * e.z; acc.w += sa[w] * e.w;
            }
        }
        short4v s;
        s.x = (short)rnebf(acc.x); s.y = (short)rnebf(acc.y);
        s.z = (short)rnebf(acc.z); s.w = (short)rnebf(acc.w);
        *(short4v*)(ctxb + (size_t)b * H + h4 * 4) = s;
    }
}

// sum 8 fc1 partials + bias -> tanh -> o2 (fp32, d_out) + o2b (bf16)
__global__ void fc1_fin_k(const float* __restrict__ part, const float* __restrict__ bias,
                          float* __restrict__ o2, short* __restrict__ o2b)
{
    const int idx = blockIdx.x * 256 + threadIdx.x;   // < 128*1024
    const int n = idx & 1023;
    float v = bias[n];
    #pragma unroll
    for (int i = 0; i < 8; ++i) v += part[idx + i * 131072];
    v = tanhf(v);
    o2[idx] = v;
    o2b[idx] = (short)rnebf(v);
}

// in-place log_softmax per row over V
__global__ __launch_bounds__(1024) void lsm_k(float* __restrict__ y)
{
    __shared__ float sm[16], ss[16], slse;
    const int b = blockIdx.x, t = threadIdx.x;
    float* row = y + (size_t)b * V;
    float m = -1e30f, s = 0.f;
    for (int v4 = t; v4 < V / 4; v4 += 1024) {
        const float4 x = ((const float4*)row)[v4];
        const float mm = fmaxf(fmaxf(x.x, x.y), fmaxf(x.z, x.w));
        if (mm > m) { s *= expf(m - mm); m = mm; }
        s += expf(x.x - m) + expf(x.y - m) + expf(x.z - m) + expf(x.w - m);
    }
    for (int off = 32; off > 0; off >>= 1) {
        const float mo = __shfl_down(m, off), so = __shfl_down(s, off);
        const float mn = fmaxf(m, mo);
        s = s * expf(m - mn) + so * expf(mo - mn);
        m = mn;
    }
    const int wv = t >> 6, lane = t & 63;
    if (lane == 0) { sm[wv] = m; ss[wv] = s; }
    __syncthreads();
    if (t == 0) {
        float M = sm[0], S = ss[0];
        for (int i = 1; i < 16; ++i) {
            const float mn = fmaxf(M, sm[i]);
            S = S * expf(M - mn) + ss[i] * expf(sm[i] - mn);
            M = mn;
        }
        slse = M + logf(S);
    }
    __syncthreads();
    const float lse = slse;
    for (int v4 = t; v4 < V / 4; v4 += 1024) {
        float4 x = ((const float4*)row)[v4];
        x.x -= lse; x.y -= lse; x.z -= lse; x.w -= lse;
        ((float4*)row)[v4] = x;
    }
}

} // namespace

extern "C" void kernel_launch(void* const* d_in, const int* in_sizes, int n_in,
                              void* d_out, int out_size, void* d_ws, size_t ws_size,
                              hipStream_t stream)
{
    const int*   Sp   = (const int*)d_in[0];
    const float* enc  = (const float*)d_in[1];
    const int*   word = (const int*)d_in[2];
    const float* h0   = (const float*)d_in[3];
    const float* c0   = (const float*)d_in[4];
    const float* emb  = (const float*)d_in[5];
    const float* Wih  = (const float*)d_in[6];
    const float* Whh  = (const float*)d_in[7];
    const float* bih  = (const float*)d_in[8];
    const float* bhh  = (const float*)d_in[9];
    const float* aw1  = (const float*)d_in[10];
    const float* ab1  = (const float*)d_in[11];
    const float* aw2  = (const float*)d_in[12];
    const float* ab2  = (const float*)d_in[13];
    const float* f1w  = (const float*)d_in[14];
    const float* f1b  = (const float*)d_in[15];
    const float* f2w  = (const float*)d_in[16];
    const float* f2b  = (const float*)d_in[17];

    float* outp = (float*)d_out;
    float* y    = outp;                       // 128*32000
    float* o2   = y  + (size_t)B * V;         // 128*1024
    float* hN   = o2 + (size_t)B * H;         // 2*128*1024
    float* cN   = hN + 2 * (size_t)B * H;     // 2*128*1024
    float* aO   = cN + 2 * (size_t)B * H;     // 128*21

    char* wsp = (char*)d_ws;
    short* xh   = (short*)wsp;  wsp += (size_t)B * H * 2;
    short* xm   = (short*)wsp;  wsp += (size_t)B * H * 2;
    short* xl   = (short*)wsp;  wsp += (size_t)B * H * 2;
    short* h0h  = (short*)wsp;  wsp += (size_t)2 * B * H * 2;
    short* h0m  = (short*)wsp;  wsp += (size_t)2 * B * H * 2;
    short* h0l  = (short*)wsp;  wsp += (size_t)2 * B * H * 2;
    short* ctxb = (short*)wsp;  wsp += (size_t)B * H * 2;
    short* o2b  = (short*)wsp;  wsp += (size_t)B * H * 2;
    float* part = (float*)wsp;  wsp += (size_t)4 * B * 4 * H * 4;  // 8 MB
    float* pbuf = (float*)wsp;  wsp += B * 4;
    int*   wsi  = (int*)wsp;    wsp += B * 4;
    int*   wei  = (int*)wsp;    wsp += B * 4;

    embed_split_k<<<dim3(B), dim3(256), 0, stream>>>(word, emb, xh, xm, xl);
    split3_k<<<dim3(2 * B * H / 1024), dim3(256), 0, stream>>>(h0, h0h, h0m, h0l);

    for (int l = 0; l < 2; ++l) {
        gemm_x3<<<dim3(64, 4), dim3(256), 0, stream>>>(
            xh, xm, xl,
            h0h + (size_t)l * B * H, h0m + (size_t)l * B * H, h0l + (size_t)l * B * H,
            Wih + (size_t)l * 4 * H * H, Whh + (size_t)l * 4 * H * H,
            4 * H, part);
        lstm_cell_k<<<dim3(B * H / 256), dim3(256), 0, stream>>>(
            part, bih + (size_t)l * 4 * H, bhh + (size_t)l * 4 * H,
            c0 + (size_t)l * B * H,
            hN + (size_t)l * B * H, cN + (size_t)l * B * H, xh, xm, xl);
    }

    const float* hfin = hN + (size_t)B * H;  // last layer h (fp32)

    // attn position: t1pre = h @ w1^T (split3 MFMA, 2 K-partials) -> finish
    gemm_x3<<<dim3(8, 2), dim3(256), 0, stream>>>(
        xh, xm, xl, xh, xm, xl, aw1, aw1, 512, part);
    attn_fin_k<<<dim3(B), dim3(256), 0, stream>>>(part, ab1, aw2, ab2, Sp, pbuf, wsi, wei);

    attn_ctx_k<<<dim3(B), dim3(256), 0, stream>>>(hfin, enc, pbuf, wsi, wei, aO, ctxb);

    // fc1: [ctx | out] @ f1w^T -> 8 split-K partials -> tanh
    fc1_gemm<<<dim3(16, 8), dim3(256), 0, stream>>>(ctxb, xh, f1w, part);
    fc1_fin_k<<<dim3(B * H / 256), dim3(256), 0, stream>>>(part, f1b, o2, o2b);

    // fc2: o2 @ f2w^T + b -> logits straight into y
    fc2_gemm<<<dim3(V / 128), dim3(256), 0, stream>>>(o2b, f2w, f2b, y);

    lsm_k<<<dim3(B), dim3(1024), 0, stream>>>(y);
}

// Round 6
// 243.971 us; speedup vs baseline: 2.8926x; 1.1646x over previous
//
#include <hip/hip_runtime.h>
#include <math.h>

namespace {

constexpr int B    = 128;
constexpr int H    = 1024;
constexpr int V    = 32000;
constexpr int WSZ  = 10;
constexpr int MAXW = 2 * WSZ + 1;   // 21

typedef __attribute__((ext_vector_type(8))) short bf16x8;
typedef __attribute__((ext_vector_type(4))) short short4v;
typedef __attribute__((ext_vector_type(4))) float f32x4;

__device__ __forceinline__ float sigf(float x) { return 1.0f / (1.0f + expf(-x)); }

__device__ __forceinline__ unsigned short rnebf(float f) {
    unsigned u = __float_as_uint(f);
    u += 0x7fffu + ((u >> 16) & 1u);
    return (unsigned short)(u >> 16);
}

__device__ __forceinline__ bf16x8 cvt8(const f32x4 a, const f32x4 b) {
    bf16x8 r;
    r[0] = (short)rnebf(a.x); r[1] = (short)rnebf(a.y);
    r[2] = (short)rnebf(a.z); r[3] = (short)rnebf(a.w);
    r[4] = (short)rnebf(b.x); r[5] = (short)rnebf(b.y);
    r[6] = (short)rnebf(b.z); r[7] = (short)rnebf(b.w);
    return r;
}

struct S3 { short h, m, l; };

// exact 3-way truncation split: x == h + m + l + delta, |delta| <~ 2^-24 |x|
__device__ __forceinline__ S3 split3(float x) {
    S3 r;
    const unsigned uh = __float_as_uint(x) & 0xFFFF0000u;
    const float fh = __uint_as_float(uh);
    const float r1 = x - fh;
    const unsigned um = __float_as_uint(r1) & 0xFFFF0000u;
    const float fm = __uint_as_float(um);
    const float r2 = r1 - fm;
    const unsigned ul = __float_as_uint(r2) & 0xFFFF0000u;
    r.h = (short)(uh >> 16);
    r.m = (short)(um >> 16);
    r.l = (short)(ul >> 16);
    return r;
}

__device__ __forceinline__ void split8(const f32x4 a, const f32x4 b,
                                       bf16x8& wh, bf16x8& wm, bf16x8& wl) {
    S3 s;
    s = split3(a.x); wh[0] = s.h; wm[0] = s.m; wl[0] = s.l;
    s = split3(a.y); wh[1] = s.h; wm[1] = s.m; wl[1] = s.l;
    s = split3(a.z); wh[2] = s.h; wm[2] = s.m; wl[2] = s.l;
    s = split3(a.w); wh[3] = s.h; wm[3] = s.m; wl[3] = s.l;
    s = split3(b.x); wh[4] = s.h; wm[4] = s.m; wl[4] = s.l;
    s = split3(b.y); wh[5] = s.h; wm[5] = s.m; wl[5] = s.l;
    s = split3(b.z); wh[6] = s.h; wm[6] = s.m; wl[6] = s.l;
    s = split3(b.w); wh[7] = s.h; wm[7] = s.m; wl[7] = s.l;
}

// ---------------------------------------------------------------------------
// fc2: out[128 x 32000] = A(bf16 128x1024) @ W(f32 32000x1024)^T + bias
// 4 waves/block; wave owns 32 cols (2 col-tiles share A frags).
// 2-deep register prefetch of W and A; peeled 2-chunk tail. Grid 250.
// ---------------------------------------------------------------------------
__global__ __launch_bounds__(256) void fc2_gemm(
    const short* __restrict__ A, const float* __restrict__ W,
    const float* __restrict__ bias, float* __restrict__ out)
{
    const int t = threadIdx.x;
    const int lane = t & 63;
    const int wv = t >> 6;
    const int n0 = blockIdx.x * 128 + wv * 32;
    const int m16 = lane & 15;
    const int ko8 = (lane >> 4) * 8;

    const float* wp0 = W + (size_t)(n0 + m16) * 1024 + ko8;
    const float* wp1 = W + (size_t)(n0 + 16 + m16) * 1024 + ko8;
    const short* ap  = A + (size_t)m16 * 1024 + ko8;

    f32x4 acc0[8] = {}, acc1[8] = {};

    f32x4 c0a = *(const f32x4*)(wp0);      f32x4 c0b = *(const f32x4*)(wp0 + 4);
    f32x4 c1a = *(const f32x4*)(wp1);      f32x4 c1b = *(const f32x4*)(wp1 + 4);
    f32x4 n0a = *(const f32x4*)(wp0 + 32); f32x4 n0b = *(const f32x4*)(wp0 + 36);
    f32x4 n1a = *(const f32x4*)(wp1 + 32); f32x4 n1b = *(const f32x4*)(wp1 + 36);
    bf16x8 ca[8], na[8];
    #pragma unroll
    for (int m = 0; m < 8; ++m) {
        ca[m] = *(const bf16x8*)(ap + (size_t)m * 16384);
        na[m] = *(const bf16x8*)(ap + (size_t)m * 16384 + 32);
    }

    for (int kc = 0; kc + 64 < 1024; kc += 32) {
        const int kf = kc + 64;
        const f32x4 f0a = *(const f32x4*)(wp0 + kf);
        const f32x4 f0b = *(const f32x4*)(wp0 + kf + 4);
        const f32x4 f1a = *(const f32x4*)(wp1 + kf);
        const f32x4 f1b = *(const f32x4*)(wp1 + kf + 4);
        bf16x8 fa[8];
        #pragma unroll
        for (int m = 0; m < 8; ++m)
            fa[m] = *(const bf16x8*)(ap + (size_t)m * 16384 + kf);

        const bf16x8 b0 = cvt8(c0a, c0b);
        const bf16x8 b1 = cvt8(c1a, c1b);
        #pragma unroll
        for (int m = 0; m < 8; ++m) {
            acc0[m] = __builtin_amdgcn_mfma_f32_16x16x32_bf16(ca[m], b0, acc0[m], 0, 0, 0);
            acc1[m] = __builtin_amdgcn_mfma_f32_16x16x32_bf16(ca[m], b1, acc1[m], 0, 0, 0);
        }
        c0a = n0a; c0b = n0b; c1a = n1a; c1b = n1b;
        n0a = f0a; n0b = f0b; n1a = f1a; n1b = f1b;
        #pragma unroll
        for (int m = 0; m < 8; ++m) { ca[m] = na[m]; na[m] = fa[m]; }
    }
    {   // chunk 960
        const bf16x8 b0 = cvt8(c0a, c0b);
        const bf16x8 b1 = cvt8(c1a, c1b);
        #pragma unroll
        for (int m = 0; m < 8; ++m) {
            acc0[m] = __builtin_amdgcn_mfma_f32_16x16x32_bf16(ca[m], b0, acc0[m], 0, 0, 0);
            acc1[m] = __builtin_amdgcn_mfma_f32_16x16x32_bf16(ca[m], b1, acc1[m], 0, 0, 0);
        }
    }
    {   // chunk 992
        const bf16x8 b0 = cvt8(n0a, n0b);
        const bf16x8 b1 = cvt8(n1a, n1b);
        #pragma unroll
        for (int m = 0; m < 8; ++m) {
            acc0[m] = __builtin_amdgcn_mfma_f32_16x16x32_bf16(na[m], b0, acc0[m], 0, 0, 0);
            acc1[m] = __builtin_amdgcn_mfma_f32_16x16x32_bf16(na[m], b1, acc1[m], 0, 0, 0);
        }
    }

    const float bv0 = bias[n0 + m16];
    const float bv1 = bias[n0 + 16 + m16];
    #pragma unroll
    for (int m = 0; m < 8; ++m) {
        const int rbase = m * 16 + (lane >> 4) * 4;
        #pragma unroll
        for (int r = 0; r < 4; ++r) {
            out[(size_t)(rbase + r) * V + n0 + m16]      = acc0[m][r] + bv0;
            out[(size_t)(rbase + r) * V + n0 + 16 + m16] = acc1[m][r] + bv1;
        }
    }
}

// ---------------------------------------------------------------------------
// Split-bf16 (near-fp32) MFMA GEMM. A: 128x1024 in 3 bf16 planes (row stride
// 1024). W: fp32, row stride 1024. y: src = y>>2, k0 = (y&3)*256 (K=256/block).
// LSTM: N=4096, grid (64,8). attn t1pre: N=512, grid (8,4) (src 0 only).
// 2-deep W prefetch, peeled tails.
// ---------------------------------------------------------------------------
__global__ __launch_bounds__(256, 2) void gemm_x3(
    const short* __restrict__ Ah0, const short* __restrict__ Am0, const short* __restrict__ Al0,
    const short* __restrict__ Ah1, const short* __restrict__ Am1, const short* __restrict__ Al1,
    const float* __restrict__ W0, const float* __restrict__ W1,
    int N, float* __restrict__ outbase)
{
    const int y = blockIdx.y;
    const int src = y >> 2;
    const short* Ah = src ? Ah1 : Ah0;
    const short* Am = src ? Am1 : Am0;
    const short* Al = src ? Al1 : Al0;
    const float* W  = src ? W1  : W0;
    const int k0 = (y & 3) * 256;
    float* out = outbase + (size_t)y * 128 * N;

    const int t    = threadIdx.x;
    const int lane = t & 63;
    const int wv   = t >> 6;
    const int n0   = blockIdx.x * 64 + wv * 16;
    const int m16  = lane & 15;
    const int ko8  = (lane >> 4) * 8;

    const float* wp = W + (size_t)(n0 + m16) * 1024 + k0 + ko8;
    const size_t a0 = (size_t)m16 * 1024 + k0 + ko8;

    f32x4 acc[8] = {};

    f32x4 cwa = *(const f32x4*)(wp);      f32x4 cwb = *(const f32x4*)(wp + 4);
    f32x4 nwa = *(const f32x4*)(wp + 32); f32x4 nwb = *(const f32x4*)(wp + 36);

    #define X3_CHUNK(KC, WA, WB)                                                    \
    {                                                                               \
        bf16x8 wh, wm, wl;                                                          \
        split8(WA, WB, wh, wm, wl);                                                 \
        _Pragma("unroll")                                                           \
        for (int m = 0; m < 8; ++m) {                                               \
            const size_t ao = a0 + (size_t)m * 16384 + (KC);                        \
            const bf16x8 ah = *(const bf16x8*)(Ah + ao);                            \
            const bf16x8 am = *(const bf16x8*)(Am + ao);                            \
            const bf16x8 al = *(const bf16x8*)(Al + ao);                            \
            acc[m] = __builtin_amdgcn_mfma_f32_16x16x32_bf16(ah, wh, acc[m], 0, 0, 0); \
            acc[m] = __builtin_amdgcn_mfma_f32_16x16x32_bf16(ah, wm, acc[m], 0, 0, 0); \
            acc[m] = __builtin_amdgcn_mfma_f32_16x16x32_bf16(am, wh, acc[m], 0, 0, 0); \
            acc[m] = __builtin_amdgcn_mfma_f32_16x16x32_bf16(ah, wl, acc[m], 0, 0, 0); \
            acc[m] = __builtin_amdgcn_mfma_f32_16x16x32_bf16(am, wm, acc[m], 0, 0, 0); \
            acc[m] = __builtin_amdgcn_mfma_f32_16x16x32_bf16(al, wh, acc[m], 0, 0, 0); \
        }                                                                           \
    }

    for (int kc = 0; kc + 64 < 256; kc += 32) {
        const f32x4 fwa = *(const f32x4*)(wp + kc + 64);
        const f32x4 fwb = *(const f32x4*)(wp + kc + 68);
        X3_CHUNK(kc, cwa, cwb);
        cwa = nwa; cwb = nwb; nwa = fwa; nwb = fwb;
    }
    X3_CHUNK(192, cwa, cwb);
    X3_CHUNK(224, nwa, nwb);
    #undef X3_CHUNK

    #pragma unroll
    for (int m = 0; m < 8; ++m) {
        const int rbase = m * 16 + (lane >> 4) * 4;
        #pragma unroll
        for (int r = 0; r < 4; ++r)
            out[(size_t)(rbase + r) * N + n0 + m16] = acc[m][r];
    }
}

// ---------------------------------------------------------------------------
// fc1: 16 split-K partials. y in [0,16): src=y>>3, k0=(y&7)*128. W stride 2048.
// ---------------------------------------------------------------------------
__global__ __launch_bounds__(256) void fc1_gemm(
    const short* __restrict__ A0, const short* __restrict__ A1,
    const float* __restrict__ W, float* __restrict__ outbase)
{
    const int y = blockIdx.y;
    const int src = y >> 3;
    const short* A = src ? A1 : A0;
    const int k0 = (y & 7) * 128;
    const int wk0 = src * 1024 + k0;
    float* out = outbase + (size_t)y * 128 * 1024;

    const int t    = threadIdx.x;
    const int lane = t & 63;
    const int wv   = t >> 6;
    const int n0   = blockIdx.x * 64 + wv * 16;
    const int m16  = lane & 15;
    const int ko8  = (lane >> 4) * 8;

    const float* wp = W + (size_t)(n0 + m16) * 2048 + wk0 + ko8;
    const short* ap = A + (size_t)m16 * 1024 + k0 + ko8;

    f32x4 acc[8] = {};
    f32x4 cwa = *(const f32x4*)(wp);      f32x4 cwb = *(const f32x4*)(wp + 4);
    f32x4 nwa = *(const f32x4*)(wp + 32); f32x4 nwb = *(const f32x4*)(wp + 36);

    #define FC1_CHUNK(KC, WA, WB)                                                   \
    {                                                                               \
        const bf16x8 bfr = cvt8(WA, WB);                                            \
        _Pragma("unroll")                                                           \
        for (int m = 0; m < 8; ++m) {                                               \
            const bf16x8 afr = *(const bf16x8*)(ap + (size_t)m * 16384 + (KC));     \
            acc[m] = __builtin_amdgcn_mfma_f32_16x16x32_bf16(afr, bfr, acc[m], 0, 0, 0); \
        }                                                                           \
    }

    for (int kc = 0; kc + 64 < 128; kc += 32) {
        const f32x4 fwa = *(const f32x4*)(wp + kc + 64);
        const f32x4 fwb = *(const f32x4*)(wp + kc + 68);
        FC1_CHUNK(kc, cwa, cwb);
        cwa = nwa; cwb = nwb; nwa = fwa; nwb = fwb;
    }
    FC1_CHUNK(64, cwa, cwb);
    FC1_CHUNK(96, nwa, nwb);
    #undef FC1_CHUNK

    #pragma unroll
    for (int m = 0; m < 8; ++m) {
        const int rbase = m * 16 + (lane >> 4) * 4;
        #pragma unroll
        for (int r = 0; r < 4; ++r)
            out[(size_t)(rbase + r) * 1024 + n0 + m16] = acc[m][r];
    }
}

// ---------------------------------------------------------------------------
// prep: embed lookup + split3 (blocks 0..127) and h0 split3 (blocks 128..383)
__global__ void prep_k(const int* __restrict__ word, const float* __restrict__ emb,
                       const float* __restrict__ h0,
                       short* __restrict__ xh, short* __restrict__ xm, short* __restrict__ xl,
                       short* __restrict__ h0h, short* __restrict__ h0m, short* __restrict__ h0l)
{
    const int blk = blockIdx.x, t = threadIdx.x;
    const float* src; short *dh, *dm, *dl; size_t off;
    if (blk < 128) {
        src = emb + (size_t)word[blk] * H; off = (size_t)blk * H;
        dh = xh; dm = xm; dl = xl;
    } else {
        const int i = blk - 128;
        src = h0 + (size_t)i * H; off = (size_t)i * H;
        dh = h0h; dm = h0m; dl = h0l;
    }
    const float4 v = ((const float4*)src)[t];
    short4v sh, sm, sl;
    S3 s;
    s = split3(v.x); sh.x = s.h; sm.x = s.m; sl.x = s.l;
    s = split3(v.y); sh.y = s.h; sm.y = s.m; sl.y = s.l;
    s = split3(v.z); sh.z = s.h; sm.z = s.m; sl.z = s.l;
    s = split3(v.w); sh.w = s.h; sm.w = s.m; sl.w = s.l;
    *(short4v*)(dh + off + t * 4) = sh;
    *(short4v*)(dm + off + t * 4) = sm;
    *(short4v*)(dl + off + t * 4) = sl;
}

// sum 8 partials + biases -> LSTM cell -> h (fp32), c (fp32), x splits (bf16)
__global__ void lstm_cell_k(const float* __restrict__ part,
                            const float* __restrict__ bih, const float* __restrict__ bhh,
                            const float* __restrict__ c0,
                            float* __restrict__ h_out, float* __restrict__ c_out,
                            short* __restrict__ xh, short* __restrict__ xm,
                            short* __restrict__ xl)
{
    const int idx = blockIdx.x * 256 + threadIdx.x;   // < 128*1024
    const int b = idx >> 10, hh = idx & 1023;
    const size_t base = (size_t)b * 4096;
    float g[4];
    #pragma unroll
    for (int j = 0; j < 4; ++j) {
        const int o = hh + j * H;
        float s = bih[o] + bhh[o];
        #pragma unroll
        for (int i = 0; i < 8; ++i) s += part[base + o + (size_t)i * 524288];
        g[j] = s;
    }
    const float c = sigf(g[1]) * c0[idx] + sigf(g[0]) * tanhf(g[2]);
    const float h = sigf(g[3]) * tanhf(c);
    c_out[idx] = c;
    h_out[idx] = h;
    const S3 s = split3(h);
    xh[idx] = s.h; xm[idx] = s.m; xl[idx] = s.l;
}

// fused: finish p from 4 t1pre partials -> window -> scores -> softmax*gauss
// -> a (out) and ctx (bf16)
__global__ void attn_ctx_k(const float* __restrict__ part, const float* __restrict__ b1,
                           const float* __restrict__ w2v, const float* __restrict__ b2,
                           const int* __restrict__ Sptr,
                           const float* __restrict__ x, const float* __restrict__ enc,
                           float* __restrict__ a_out, short* __restrict__ ctxb)
{
    __shared__ float red[256];
    __shared__ float so[H];
    __shared__ float swred[4][MAXW];
    __shared__ float ssc[MAXW];
    __shared__ float sa[MAXW];
    __shared__ float sp;
    __shared__ int sw0, sw1;
    const int b = blockIdx.x, t = threadIdx.x;
    const int lane = t & 63, wvv = t >> 6;

    // phase 1: p, window
    {
        const float* pa = part + (size_t)b * 512;
        float v = 0.f;
        #pragma unroll
        for (int jj = 0; jj < 2; ++jj) {
            const int j = t + jj * 256;
            const float sgm = pa[j] + pa[j + 65536] + pa[j + 2 * 65536] + pa[j + 3 * 65536] + b1[j];
            v += tanhf(sgm) * w2v[j];
        }
        red[t] = v;
        __syncthreads();
        for (int s = 128; s > 0; s >>= 1) {
            if (t < s) red[t] += red[t + s];
            __syncthreads();
        }
        if (t == 0) {
            const float S = (float)Sptr[0];
            const float sv = S * sigf(red[0] + b2[0]);
            sp  = sv;
            sw0 = (int)rintf(fmaxf(sv - (float)WSZ, 0.f));
            sw1 = (int)rintf(fminf(sv + (float)WSZ, S - 1.f));
        }
    }
    for (int h = t; h < H; h += 256) so[h] = x[(size_t)b * H + h];
    __syncthreads();
    const int w0 = sw0, w1e = sw1;
    const float pbv = sp;

    float ps[MAXW];
    #pragma unroll
    for (int w = 0; w < MAXW; ++w) ps[w] = 0.f;
    for (int h4 = t; h4 < H / 4; h4 += 256) {
        const float4 o = ((const float4*)so)[h4];
        #pragma unroll
        for (int w = 0; w < MAXW; ++w) {
            const int idx = w0 + w;
            if (idx <= w1e) {
                const float4 e = *(const float4*)(enc + ((size_t)idx * B + b) * H + h4 * 4);
                ps[w] += o.x * e.x + o.y * e.y + o.z * e.z + o.w * e.w;
            }
        }
    }
    #pragma unroll
    for (int w = 0; w < MAXW; ++w) {
        float v = ps[w];
        for (int off = 32; off > 0; off >>= 1) v += __shfl_down(v, off);
        if (lane == 0) swred[wvv][w] = v;
    }
    __syncthreads();
    if (t == 0) {
        float m = -1e30f;
        for (int w = 0; w < MAXW; ++w) {
            const float s = swred[0][w] + swred[1][w] + swred[2][w] + swred[3][w];
            ssc[w] = s;
            m = fmaxf(m, s);
        }
        float den = 0.f;
        for (int w = 0; w < MAXW; ++w) den += expf(ssc[w] - m);
        for (int w = 0; w < MAXW; ++w) {
            const int idx = w0 + w;
            const float gauss = (idx <= w1e) ? expf(((float)idx - pbv) / 50.0f) : 0.f;
            sa[w] = expf(ssc[w] - m) / den * gauss;
        }
    }
    __syncthreads();
    if (t < MAXW) a_out[b * MAXW + t] = sa[t];
    for (int h4 = t; h4 < H / 4; h4 += 256) {
        float4 acc = {0.f, 0.f, 0.f, 0.f};
        #pragma unroll
        for (int w = 0; w < MAXW; ++w) {
            const int idx = w0 + w;
            if (idx <= w1e) {
                const float4 e = *(const float4*)(enc + ((size_t)idx * B + b) * H + h4 * 4);
                acc.x += sa[w] * e.x; acc.y += sa[w] * e.y;
                acc.z += sa[w] * e.z; acc.w += sa[w] * e.w;
            }
        }
        short4v s;
        s.x = (short)rnebf(acc.x); s.y = (short)rnebf(acc.y);
        s.z = (short)rnebf(acc.z); s.w = (short)rnebf(acc.w);
        *(short4v*)(ctxb + (size_t)b * H + h4 * 4) = s;
    }
}

// sum 16 fc1 partials + bias -> tanh -> o2 (fp32, d_out) + o2b (bf16)
__global__ void fc1_fin_k(const float* __restrict__ part, const float* __restrict__ bias,
                          float* __restrict__ o2, short* __restrict__ o2b)
{
    const int idx = blockIdx.x * 256 + threadIdx.x;   // < 128*1024
    const int n = idx & 1023;
    float v = bias[n];
    #pragma unroll
    for (int i = 0; i < 16; ++i) v += part[idx + (size_t)i * 131072];
    v = tanhf(v);
    o2[idx] = v;
    o2b[idx] = (short)rnebf(v);
}

// in-place log_softmax per row over V
__global__ __launch_bounds__(1024) void lsm_k(float* __restrict__ y)
{
    __shared__ float sm[16], ss[16], slse;
    const int b = blockIdx.x, t = threadIdx.x;
    float* row = y + (size_t)b * V;
    float m = -1e30f, s = 0.f;
    for (int v4 = t; v4 < V / 4; v4 += 1024) {
        const float4 x = ((const float4*)row)[v4];
        const float mm = fmaxf(fmaxf(x.x, x.y), fmaxf(x.z, x.w));
        if (mm > m) { s *= expf(m - mm); m = mm; }
        s += expf(x.x - m) + expf(x.y - m) + expf(x.z - m) + expf(x.w - m);
    }
    for (int off = 32; off > 0; off >>= 1) {
        const float mo = __shfl_down(m, off), so = __shfl_down(s, off);
        const float mn = fmaxf(m, mo);
        s = s * expf(m - mn) + so * expf(mo - mn);
        m = mn;
    }
    const int wv = t >> 6, lane = t & 63;
    if (lane == 0) { sm[wv] = m; ss[wv] = s; }
    __syncthreads();
    if (t == 0) {
        float M = sm[0], S = ss[0];
        for (int i = 1; i < 16; ++i) {
            const float mn = fmaxf(M, sm[i]);
            S = S * expf(M - mn) + ss[i] * expf(sm[i] - mn);
            M = mn;
        }
        slse = M + logf(S);
    }
    __syncthreads();
    const float lse = slse;
    for (int v4 = t; v4 < V / 4; v4 += 1024) {
        float4 x = ((const float4*)row)[v4];
        x.x -= lse; x.y -= lse; x.z -= lse; x.w -= lse;
        ((float4*)row)[v4] = x;
    }
}

} // namespace

extern "C" void kernel_launch(void* const* d_in, const int* in_sizes, int n_in,
                              void* d_out, int out_size, void* d_ws, size_t ws_size,
                              hipStream_t stream)
{
    const int*   Sp   = (const int*)d_in[0];
    const float* enc  = (const float*)d_in[1];
    const int*   word = (const int*)d_in[2];
    const float* h0   = (const float*)d_in[3];
    const float* c0   = (const float*)d_in[4];
    const float* emb  = (const float*)d_in[5];
    const float* Wih  = (const float*)d_in[6];
    const float* Whh  = (const float*)d_in[7];
    const float* bih  = (const float*)d_in[8];
    const float* bhh  = (const float*)d_in[9];
    const float* aw1  = (const float*)d_in[10];
    const float* ab1  = (const float*)d_in[11];
    const float* aw2  = (const float*)d_in[12];
    const float* ab2  = (const float*)d_in[13];
    const float* f1w  = (const float*)d_in[14];
    const float* f1b  = (const float*)d_in[15];
    const float* f2w  = (const float*)d_in[16];
    const float* f2b  = (const float*)d_in[17];

    float* outp = (float*)d_out;
    float* y    = outp;                       // 128*32000
    float* o2   = y  + (size_t)B * V;         // 128*1024
    float* hN   = o2 + (size_t)B * H;         // 2*128*1024
    float* cN   = hN + 2 * (size_t)B * H;     // 2*128*1024
    float* aO   = cN + 2 * (size_t)B * H;     // 128*21

    char* wsp = (char*)d_ws;
    short* xh   = (short*)wsp;  wsp += (size_t)B * H * 2;
    short* xm   = (short*)wsp;  wsp += (size_t)B * H * 2;
    short* xl   = (short*)wsp;  wsp += (size_t)B * H * 2;
    short* h0h  = (short*)wsp;  wsp += (size_t)2 * B * H * 2;
    short* h0m  = (short*)wsp;  wsp += (size_t)2 * B * H * 2;
    short* h0l  = (short*)wsp;  wsp += (size_t)2 * B * H * 2;
    short* ctxb = (short*)wsp;  wsp += (size_t)B * H * 2;
    short* o2b  = (short*)wsp;  wsp += (size_t)B * H * 2;
    float* part = (float*)wsp;  wsp += (size_t)8 * B * 4 * H * 4;  // 16 MB
    float* pbuf = (float*)wsp;  wsp += B * 4;  (void)pbuf;

    prep_k<<<dim3(384), dim3(256), 0, stream>>>(word, emb, h0, xh, xm, xl, h0h, h0m, h0l);

    for (int l = 0; l < 2; ++l) {
        gemm_x3<<<dim3(64, 8), dim3(256), 0, stream>>>(
            xh, xm, xl,
            h0h + (size_t)l * B * H, h0m + (size_t)l * B * H, h0l + (size_t)l * B * H,
            Wih + (size_t)l * 4 * H * H, Whh + (size_t)l * 4 * H * H,
            4 * H, part);
        lstm_cell_k<<<dim3(B * H / 256), dim3(256), 0, stream>>>(
            part, bih + (size_t)l * 4 * H, bhh + (size_t)l * 4 * H,
            c0 + (size_t)l * B * H,
            hN + (size_t)l * B * H, cN + (size_t)l * B * H, xh, xm, xl);
    }

    const float* hfin = hN + (size_t)B * H;  // last layer h (fp32)

    // attn position pre-GEMM: t1pre = h @ w1^T (split3 MFMA, 4 K-partials)
    gemm_x3<<<dim3(8, 4), dim3(256), 0, stream>>>(
        xh, xm, xl, xh, xm, xl, aw1, aw1, 512, part);
    attn_ctx_k<<<dim3(B), dim3(256), 0, stream>>>(
        part, ab1, aw2, ab2, Sp, hfin, enc, aO, ctxb);

    // fc1: [ctx | out] @ f1w^T -> 16 split-K partials -> tanh
    fc1_gemm<<<dim3(16, 16), dim3(256), 0, stream>>>(ctxb, xh, f1w, part);
    fc1_fin_k<<<dim3(B * H / 256), dim3(256), 0, stream>>>(part, f1b, o2, o2b);

    // fc2: o2 @ f2w^T + b -> logits straight into y
    fc2_gemm<<<dim3(V / 128), dim3(256), 0, stream>>>(o2b, f2w, f2b, y);

    lsm_k<<<dim3(B), dim3(1024), 0, stream>>>(y);
}